// Round 1
// baseline (120.162 us; speedup 1.0000x reference)
//
#include <hip/hip_runtime.h>

// Focus: space-to-depth(2x2) + 1x1 conv (3*4=12 -> 64) + BatchNorm(inference) + SiLU
// x: [16,3,640,640] f32, W: [64,12] f32, out: [16,64,320,320] f32
// Memory-bound: ~78.6 MB read + ~419.4 MB write. Target ~80-110 us.

namespace {
constexpr int B    = 16;
constexpr int CIN  = 3;
constexpr int CH   = 640;
constexpr int CW   = 640;
constexpr int COUT = 64;
constexpr int OH   = 320;
constexpr int OW   = 320;
constexpr float EPS = 1e-5f;

constexpr int TPB = 256;
constexpr int PAIRS_PER_ROW = OW / 2;               // 160 float2-pairs per output row
constexpr int PAIRS_PER_IMG = OH * PAIRS_PER_ROW;   // 51200
constexpr int TOTAL_PAIRS   = B * PAIRS_PER_IMG;    // 819200
constexpr int PP = 2;                               // pairs per thread
constexpr int GRID = TOTAL_PAIRS / (TPB * PP);      // 1600 blocks, exact
}

__global__ __launch_bounds__(TPB) void focus_fused(
    const float* __restrict__ x, const float* __restrict__ W,
    const float* __restrict__ gamma, const float* __restrict__ beta,
    const float* __restrict__ rmean, const float* __restrict__ rvar,
    float* __restrict__ out)
{
    // BN-folded weights + shift in LDS (broadcast reads only)
    __shared__ __attribute__((aligned(16))) float Ws[COUT * 12];
    __shared__ float Sh[COUT];

    const int tid = threadIdx.x;
#pragma unroll
    for (int i = 0; i < 3; ++i) {
        int idx = tid + i * TPB;                 // 0..767
        int o = idx / 12;
        float sc = gamma[o] * rsqrtf(rvar[o] + EPS);
        Ws[idx] = W[idx] * sc;
    }
    if (tid < COUT) {
        float sc = gamma[tid] * rsqrtf(rvar[tid] + EPS);
        Sh[tid] = beta[tid] - rmean[tid] * sc;
    }
    __syncthreads();

    // Load inputs: each thread handles PP pairs of consecutive output columns.
    // For a pair index t: output cols 2t,2t+1  <-  input cols 4t..4t+3 (float4).
    float v[PP][CIN][2][4];   // [pair][cin][row parity][col within float4]
    int   obase[PP];          // output offset of (b, o=0, h, 2t)

#pragma unroll
    for (int k = 0; k < PP; ++k) {
        int pp  = blockIdx.x * (TPB * PP) + k * TPB + tid;
        int b   = pp / PAIRS_PER_IMG;
        int rem = pp - b * PAIRS_PER_IMG;
        int h   = rem / PAIRS_PER_ROW;
        int t   = rem - h * PAIRS_PER_ROW;
        const float* xb = x + (((long)b * CIN) * CH + 2 * h) * (long)CW + 4 * t;
#pragma unroll
        for (int c = 0; c < CIN; ++c) {
#pragma unroll
            for (int r = 0; r < 2; ++r) {
                float4 f = *reinterpret_cast<const float4*>(xb + ((long)c * CH + r) * CW);
                v[k][c][r][0] = f.x; v[k][c][r][1] = f.y;
                v[k][c][r][2] = f.z; v[k][c][r][3] = f.w;
            }
        }
        obase[k] = (b * COUT) * (OH * OW) + h * OW + 2 * t;
    }

    // Channel loop: 3 broadcast ds_read_b128 per o, 12 FMA per output, SiLU, float2 store.
#pragma unroll 2
    for (int o = 0; o < COUT; ++o) {
        float wr[12];
        *reinterpret_cast<float4*>(&wr[0]) = *reinterpret_cast<const float4*>(&Ws[o * 12 + 0]);
        *reinterpret_cast<float4*>(&wr[4]) = *reinterpret_cast<const float4*>(&Ws[o * 12 + 4]);
        *reinterpret_cast<float4*>(&wr[8]) = *reinterpret_cast<const float4*>(&Ws[o * 12 + 8]);
        const float sh = Sh[o];
#pragma unroll
        for (int k = 0; k < PP; ++k) {
            float2 rs;
#pragma unroll
            for (int j = 0; j < 2; ++j) {
                // concat order: s=0 (even r, even c), s=1 (odd r, even c),
                //               s=2 (even r, odd c), s=3 (odd r, odd c); c' = s*3 + c
                float acc = sh;
                acc += wr[0]  * v[k][0][0][2 * j];
                acc += wr[1]  * v[k][1][0][2 * j];
                acc += wr[2]  * v[k][2][0][2 * j];
                acc += wr[3]  * v[k][0][1][2 * j];
                acc += wr[4]  * v[k][1][1][2 * j];
                acc += wr[5]  * v[k][2][1][2 * j];
                acc += wr[6]  * v[k][0][0][2 * j + 1];
                acc += wr[7]  * v[k][1][0][2 * j + 1];
                acc += wr[8]  * v[k][2][0][2 * j + 1];
                acc += wr[9]  * v[k][0][1][2 * j + 1];
                acc += wr[10] * v[k][1][1][2 * j + 1];
                acc += wr[11] * v[k][2][1][2 * j + 1];
                float sg = 1.0f / (1.0f + __expf(-acc));
                float val = acc * sg;
                if (j == 0) rs.x = val; else rs.y = val;
            }
            *reinterpret_cast<float2*>(out + obase[k] + o * (OH * OW)) = rs;
        }
    }
}

extern "C" void kernel_launch(void* const* d_in, const int* in_sizes, int n_in,
                              void* d_out, int out_size, void* d_ws, size_t ws_size,
                              hipStream_t stream) {
    const float* x     = (const float*)d_in[0];
    const float* W     = (const float*)d_in[1];
    const float* gamma = (const float*)d_in[2];
    const float* beta  = (const float*)d_in[3];
    const float* rmean = (const float*)d_in[4];
    const float* rvar  = (const float*)d_in[5];
    float* out = (float*)d_out;
    focus_fused<<<GRID, TPB, 0, stream>>>(x, W, gamma, beta, rmean, rvar, out);
}

// Round 3
// 116.727 us; speedup vs baseline: 1.0294x; 1.0294x over previous
//
#include <hip/hip_runtime.h>

// Focus: space-to-depth(2x2) + 1x1 conv (12 -> 64) + BatchNorm(inference) + SiLU
// x: [16,3,640,640] f32, W: [64,12] f32, out: [16,64,320,320] f32
// Memory-bound: ~78.6 MB read + ~419.4 MB write. Ceiling (fill-kernel BW ~6.9 TB/s) ~75-85 us.
// R3: same as R2 but ext_vector_type float4 for nontemporal builtins (HIP float4 is a
// struct and rejected by __builtin_nontemporal_*).

typedef float f32x4 __attribute__((ext_vector_type(4)));

namespace {
constexpr int B    = 16;
constexpr int CIN  = 3;
constexpr int CH   = 640;
constexpr int CW   = 640;
constexpr int COUT = 64;
constexpr int OH   = 320;
constexpr int OW   = 320;
constexpr float EPS = 1e-5f;

constexpr int TPB = 256;
constexpr int QPR = OW / 4;            // 80 quads (4 out-cols) per row
constexpr int QPI = OH * QPR;          // 25600 per image
constexpr int TOTAL_Q = B * QPI;       // 409600
constexpr int GRID = TOTAL_Q / TPB;    // 1600 blocks, exact
}

__global__ __launch_bounds__(TPB) void focus_fused(
    const float* __restrict__ x, const float* __restrict__ W,
    const float* __restrict__ gamma, const float* __restrict__ beta,
    const float* __restrict__ rmean, const float* __restrict__ rvar,
    float* __restrict__ out)
{
    __shared__ __attribute__((aligned(16))) float Ws[COUT * 12];
    __shared__ float Sh[COUT];

    const int tid = threadIdx.x;
#pragma unroll
    for (int i = 0; i < 3; ++i) {
        int idx = tid + i * TPB;                 // 0..767
        int o = idx / 12;
        float sc = gamma[o] * rsqrtf(rvar[o] + EPS);
        Ws[idx] = W[idx] * sc;
    }
    if (tid < COUT) {
        float sc = gamma[tid] * rsqrtf(rvar[tid] + EPS);
        Sh[tid] = beta[tid] - rmean[tid] * sc;
    }
    __syncthreads();

    // Each thread: 4 consecutive output columns (one quad) of one output row.
    // Input cols 8u..8u+7 (2x float4), rows 2h,2h+1, channels 0..2 -> 12 float4 loads.
    const int q   = blockIdx.x * TPB + tid;
    const int b   = q / QPI;
    const int rem = q - b * QPI;
    const int h   = rem / QPR;
    const int u   = rem - h * QPR;
    const float* xb = x + (((long)b * CIN) * CH + 2 * h) * (long)CW + 8 * u;

    float va[CIN][2][8];   // [cin][row parity][col 0..7]
#pragma unroll
    for (int c = 0; c < CIN; ++c) {
#pragma unroll
        for (int r = 0; r < 2; ++r) {
            const float* p = xb + ((long)c * CH + r) * CW;
            f32x4 f0 = __builtin_nontemporal_load(reinterpret_cast<const f32x4*>(p));
            f32x4 f1 = __builtin_nontemporal_load(reinterpret_cast<const f32x4*>(p) + 1);
            va[c][r][0] = f0.x; va[c][r][1] = f0.y; va[c][r][2] = f0.z; va[c][r][3] = f0.w;
            va[c][r][4] = f1.x; va[c][r][5] = f1.y; va[c][r][6] = f1.z; va[c][r][7] = f1.w;
        }
    }

    float* ob = out + ((long)b * COUT) * (OH * OW) + h * OW + 4 * u;

    // concat order: c' = s*3 + c with s: 0=(even r,even c) 1=(odd r,even c)
    //                                   2=(even r,odd c)  3=(odd r,odd c)
#pragma unroll 2
    for (int o = 0; o < COUT; ++o) {
        float wr[12];
        *reinterpret_cast<f32x4*>(&wr[0]) = *reinterpret_cast<const f32x4*>(&Ws[o * 12 + 0]);
        *reinterpret_cast<f32x4*>(&wr[4]) = *reinterpret_cast<const f32x4*>(&Ws[o * 12 + 4]);
        *reinterpret_cast<f32x4*>(&wr[8]) = *reinterpret_cast<const f32x4*>(&Ws[o * 12 + 8]);
        const float sh = Sh[o];

        f32x4 rs;
#pragma unroll
        for (int m = 0; m < 4; ++m) {
            const int e = 2 * m, d = 2 * m + 1;   // even / odd input col within the 8
            float acc = sh;
            acc += wr[0]  * va[0][0][e];
            acc += wr[1]  * va[1][0][e];
            acc += wr[2]  * va[2][0][e];
            acc += wr[3]  * va[0][1][e];
            acc += wr[4]  * va[1][1][e];
            acc += wr[5]  * va[2][1][e];
            acc += wr[6]  * va[0][0][d];
            acc += wr[7]  * va[1][0][d];
            acc += wr[8]  * va[2][0][d];
            acc += wr[9]  * va[0][1][d];
            acc += wr[10] * va[1][1][d];
            acc += wr[11] * va[2][1][d];
            // SiLU: x * sigmoid(x); sigmoid = rcp(1 + exp2(-x*log2e))
            float t = __builtin_amdgcn_exp2f(acc * -1.44269504088896f);
            float s = __builtin_amdgcn_rcpf(1.0f + t);
            rs[m] = acc * s;
        }
        __builtin_nontemporal_store(rs, reinterpret_cast<f32x4*>(ob + o * (OH * OW)));
    }
}

extern "C" void kernel_launch(void* const* d_in, const int* in_sizes, int n_in,
                              void* d_out, int out_size, void* d_ws, size_t ws_size,
                              hipStream_t stream) {
    const float* x     = (const float*)d_in[0];
    const float* W     = (const float*)d_in[1];
    const float* gamma = (const float*)d_in[2];
    const float* beta  = (const float*)d_in[3];
    const float* rmean = (const float*)d_in[4];
    const float* rvar  = (const float*)d_in[5];
    float* out = (float*)d_out;
    focus_fused<<<GRID, TPB, 0, stream>>>(x, W, gamma, beta, rmean, rvar, out);
}